// Round 1
// baseline (2477.850 us; speedup 1.0000x reference)
//
#include <hip/hip_runtime.h>
#include <math.h>

// MultiHeadAttn fp32 baseline for MI355X (gfx950).
// Pipeline: 3x projection GEMM -> flash-style causal attention -> output GEMM.
// All fp32 (CDNA4 has no fp32 MFMA; this is a VALU-bound baseline to anchor
// counters before moving matmuls to bf16 MFMA).

constexpr int B  = 4;
constexpr int S  = 2048;
constexpr int H  = 16;
constexpr int DM = 1024;
constexpr int DK = 64;
constexpr int DV = 64;
constexpr int M  = B * S;  // 8192 rows

// ---------------------------------------------------------------------------
// Tiled GEMM: X[M,DM] @ W[DM,1024] + bias -> dst
// MODE 0: dst layout [B,H,S,64]  (each 64-wide column tile == one head),
//         result scaled by `scale` (used to pre-scale Q by 1/sqrt(DK)).
// MODE 1: dst layout row-major [M,1024].
// Block: 256 threads as 16x16, each thread computes a 4x4 micro-tile.
// Tile: BM=64, BN=64, BK=16.
// ---------------------------------------------------------------------------
template <int MODE>
__global__ __launch_bounds__(256) void gemm_kernel(
    const float* __restrict__ X, const float* __restrict__ W,
    const float* __restrict__ bias, float* __restrict__ dst, float scale)
{
    constexpr int BM = 64, BN = 64, BK = 16;
    __shared__ float As[BK][BM + 4];  // [k][m]
    __shared__ float Bs[BK][BN + 4];  // [k][n]

    const int t  = threadIdx.x;
    const int tx = t & 15;        // 0..15 -> 4 cols each
    const int ty = t >> 4;        // 0..15 -> 4 rows each
    const int row0 = blockIdx.y * BM;
    const int col0 = blockIdx.x * BN;

    // A-tile loader: 64 rows x 16 k, one float4 per thread along k
    const int arow = t >> 2;            // 0..63
    const int ak4  = (t & 3) << 2;      // 0,4,8,12
    // B-tile loader: 16 rows x 64 cols, one float4 per thread along n
    const int brow = t >> 4;            // 0..15
    const int bc4  = (t & 15) << 2;     // 0..60

    float acc[4][4] = {};

    for (int k0 = 0; k0 < DM; k0 += BK) {
        float4 av = *reinterpret_cast<const float4*>(
            &X[(size_t)(row0 + arow) * DM + k0 + ak4]);
        As[ak4 + 0][arow] = av.x;
        As[ak4 + 1][arow] = av.y;
        As[ak4 + 2][arow] = av.z;
        As[ak4 + 3][arow] = av.w;
        *reinterpret_cast<float4*>(&Bs[brow][bc4]) =
            *reinterpret_cast<const float4*>(
                &W[(size_t)(k0 + brow) * 1024 + col0 + bc4]);
        __syncthreads();

        #pragma unroll
        for (int kk = 0; kk < BK; ++kk) {
            float4 a = *reinterpret_cast<const float4*>(&As[kk][ty << 2]);
            float4 b = *reinterpret_cast<const float4*>(&Bs[kk][tx << 2]);
            float va[4] = {a.x, a.y, a.z, a.w};
            float vb[4] = {b.x, b.y, b.z, b.w};
            #pragma unroll
            for (int i = 0; i < 4; ++i)
                #pragma unroll
                for (int j = 0; j < 4; ++j)
                    acc[i][j] = fmaf(va[i], vb[j], acc[i][j]);
        }
        __syncthreads();
    }

    // epilogue
    #pragma unroll
    for (int i = 0; i < 4; ++i) {
        const int r = row0 + (ty << 2) + i;
        const int c = col0 + (tx << 2);
        float4 o;
        o.x = (acc[i][0] + bias[c + 0]) * scale;
        o.y = (acc[i][1] + bias[c + 1]) * scale;
        o.z = (acc[i][2] + bias[c + 2]) * scale;
        o.w = (acc[i][3] + bias[c + 3]) * scale;
        if (MODE == 0) {
            // dst[b][h][s][d], h == blockIdx.x, d = c - col0
            const int bb = r / S, ss = r % S;
            const int hh = blockIdx.x;
            float* p = &dst[(((size_t)(bb * H + hh) * S + ss) << 6) + (tx << 2)];
            *reinterpret_cast<float4*>(p) = o;
        } else {
            *reinterpret_cast<float4*>(&dst[(size_t)r * 1024 + c]) = o;
        }
    }
}

// ---------------------------------------------------------------------------
// Flash-style causal attention, fp32.
// Q,K,V layout [B,H,S,64] (Q pre-scaled by 1/sqrt(DK)).
// Out layout [B,S,H,64] (== [M, 1024] row-major for the output GEMM).
// Block: 256 threads (16x16), QBLK = KBLK = 64, 4x4 micro-tiles.
// Grid: (S/64, B*H).
// ---------------------------------------------------------------------------
__global__ __launch_bounds__(256) void attn_kernel(
    const float* __restrict__ Q, const float* __restrict__ K,
    const float* __restrict__ V, float* __restrict__ Out)
{
    __shared__ float Qt[DK][64 + 4];   // [d][q]
    __shared__ float Kt[DK][64 + 4];   // [d][k]
    __shared__ float Vs[64][DV + 4];   // [k][d]
    __shared__ float Pt[64][64 + 4];   // [k][q]

    const int t  = threadIdx.x;
    const int tx = t & 15;             // 4 cols each
    const int ty = t >> 4;             // 4 rows each
    const int q0 = blockIdx.x << 6;
    const int bh = blockIdx.y;         // b*H + h
    const size_t base = (size_t)bh * S * DK;

    // load Q tile, transposed into Qt[d][q]
    #pragma unroll
    for (int it = 0; it < 4; ++it) {
        int idx = t + it * 256;            // 0..1023 float4 slots
        int qr  = idx >> 4;                // 0..63
        int d4  = (idx & 15) << 2;         // 0..60
        float4 qv = *reinterpret_cast<const float4*>(
            &Q[base + (size_t)(q0 + qr) * DK + d4]);
        Qt[d4 + 0][qr] = qv.x;
        Qt[d4 + 1][qr] = qv.y;
        Qt[d4 + 2][qr] = qv.z;
        Qt[d4 + 3][qr] = qv.w;
    }

    float o[4][4] = {};
    float mrow[4] = {-INFINITY, -INFINITY, -INFINITY, -INFINITY};
    float lrow[4] = {};

    const int nkv = (q0 >> 6) + 1;  // causal: tiles k0 = 0 .. q0
    for (int kt = 0; kt < nkv; ++kt) {
        const int k0 = kt << 6;
        __syncthreads();  // protect Qt (first iter) / Kt,Vs,Pt (later iters)

        #pragma unroll
        for (int it = 0; it < 4; ++it) {
            int idx = t + it * 256;
            int kr  = idx >> 4;
            int d4  = (idx & 15) << 2;
            float4 kv = *reinterpret_cast<const float4*>(
                &K[base + (size_t)(k0 + kr) * DK + d4]);
            Kt[d4 + 0][kr] = kv.x;
            Kt[d4 + 1][kr] = kv.y;
            Kt[d4 + 2][kr] = kv.z;
            Kt[d4 + 3][kr] = kv.w;
            float4 vv = *reinterpret_cast<const float4*>(
                &V[base + (size_t)(k0 + kr) * DK + d4]);
            *reinterpret_cast<float4*>(&Vs[kr][d4]) = vv;
        }
        __syncthreads();

        // scores: sc[i][j] = sum_d Qt[d][qi] * Kt[d][kj]
        float sc[4][4] = {};
        #pragma unroll 16
        for (int d = 0; d < DK; ++d) {
            float4 a = *reinterpret_cast<const float4*>(&Qt[d][ty << 2]);
            float4 b = *reinterpret_cast<const float4*>(&Kt[d][tx << 2]);
            float va[4] = {a.x, a.y, a.z, a.w};
            float vb[4] = {b.x, b.y, b.z, b.w};
            #pragma unroll
            for (int i = 0; i < 4; ++i)
                #pragma unroll
                for (int j = 0; j < 4; ++j)
                    sc[i][j] = fmaf(va[i], vb[j], sc[i][j]);
        }

        // causal mask (only the diagonal tile needs it)
        if (k0 == q0) {
            #pragma unroll
            for (int i = 0; i < 4; ++i)
                #pragma unroll
                for (int j = 0; j < 4; ++j)
                    if (((tx << 2) + j) > ((ty << 2) + i))
                        sc[i][j] = -INFINITY;
        }

        // online softmax; each score row is spread across 16 lanes (same ty)
        #pragma unroll
        for (int i = 0; i < 4; ++i) {
            float mx = fmaxf(fmaxf(sc[i][0], sc[i][1]),
                             fmaxf(sc[i][2], sc[i][3]));
            #pragma unroll
            for (int off = 1; off < 16; off <<= 1)
                mx = fmaxf(mx, __shfl_xor(mx, off));
            const float mnew  = fmaxf(mrow[i], mx);
            const float alpha = expf(mrow[i] - mnew);  // exp(-inf)=0 first time
            float ps = 0.f;
            #pragma unroll
            for (int j = 0; j < 4; ++j) {
                sc[i][j] = expf(sc[i][j] - mnew);      // exp(-inf - m) = 0
                ps += sc[i][j];
            }
            #pragma unroll
            for (int off = 1; off < 16; off <<= 1)
                ps += __shfl_xor(ps, off);
            lrow[i] = lrow[i] * alpha + ps;
            mrow[i] = mnew;
            #pragma unroll
            for (int j = 0; j < 4; ++j) o[i][j] *= alpha;
        }

        // write P transposed: Pt[k][q]
        #pragma unroll
        for (int i = 0; i < 4; ++i)
            #pragma unroll
            for (int j = 0; j < 4; ++j)
                Pt[(tx << 2) + j][(ty << 2) + i] = sc[i][j];
        __syncthreads();

        // O[qi][d] += P[qi][k] * V[k][d]
        #pragma unroll 16
        for (int kk = 0; kk < 64; ++kk) {
            float4 p = *reinterpret_cast<const float4*>(&Pt[kk][ty << 2]);
            float4 v = *reinterpret_cast<const float4*>(&Vs[kk][tx << 2]);
            float vp[4] = {p.x, p.y, p.z, p.w};
            float vv[4] = {v.x, v.y, v.z, v.w};
            #pragma unroll
            for (int i = 0; i < 4; ++i)
                #pragma unroll
                for (int j = 0; j < 4; ++j)
                    o[i][j] = fmaf(vp[i], vv[j], o[i][j]);
        }
    }

    // normalize + store to [b, s, h, d]
    const int bb = bh >> 4, hh = bh & 15;
    #pragma unroll
    for (int i = 0; i < 4; ++i) {
        const float inv = 1.0f / lrow[i];
        const int ss = q0 + (ty << 2) + i;
        float4 ov;
        ov.x = o[i][0] * inv;
        ov.y = o[i][1] * inv;
        ov.z = o[i][2] * inv;
        ov.w = o[i][3] * inv;
        float* p = &Out[(((size_t)(bb * S + ss) * H + hh) << 6) + (tx << 2)];
        *reinterpret_cast<float4*>(p) = ov;
    }
}

// ---------------------------------------------------------------------------
extern "C" void kernel_launch(void* const* d_in, const int* in_sizes, int n_in,
                              void* d_out, int out_size, void* d_ws, size_t ws_size,
                              hipStream_t stream)
{
    const float* x  = (const float*)d_in[0];
    // d_in[1] = attn_mask (bool) — causal mask is implemented analytically.
    const float* Wq = (const float*)d_in[2];
    const float* bq = (const float*)d_in[3];
    const float* Wk = (const float*)d_in[4];
    const float* bk = (const float*)d_in[5];
    const float* Wv = (const float*)d_in[6];
    const float* bv = (const float*)d_in[7];
    const float* Wo = (const float*)d_in[8];
    const float* bo = (const float*)d_in[9];
    float* out = (float*)d_out;

    float* ws = (float*)d_ws;
    const size_t qkv_elems = (size_t)B * H * S * DK;  // 8,388,608
    float* q    = ws;
    float* k    = q + qkv_elems;
    float* v    = k + qkv_elems;
    float* attn = v + qkv_elems;  // [B,S,H,DV] == [M,1024]

    const dim3 blk(256);
    const dim3 gemm_grid(16, M / 64);   // N=1024 -> 16, M=8192 -> 128
    const float qscale = 0.125f;        // 1/sqrt(DK)

    gemm_kernel<0><<<gemm_grid, blk, 0, stream>>>(x, Wq, bq, q, qscale);
    gemm_kernel<0><<<gemm_grid, blk, 0, stream>>>(x, Wk, bk, k, 1.0f);
    gemm_kernel<0><<<gemm_grid, blk, 0, stream>>>(x, Wv, bv, v, 1.0f);

    attn_kernel<<<dim3(S / 64, B * H), blk, 0, stream>>>(q, k, v, attn);

    gemm_kernel<1><<<gemm_grid, blk, 0, stream>>>(attn, Wo, bo, out, 1.0f);
}

// Round 3
// 480.619 us; speedup vs baseline: 5.1555x; 5.1555x over previous
//
#include <hip/hip_runtime.h>
#include <math.h>

// MultiHeadAttn bf16-MFMA pipeline for MI355X (gfx950).
// cast/transpose prep -> 3x MFMA projection GEMM -> V transpose ->
// flash-causal MFMA attention -> MFMA output GEMM (fp32 out).

typedef __attribute__((ext_vector_type(8))) short short8;   // 8 bf16 = 4 VGPR
typedef __attribute__((ext_vector_type(4))) float f32x4;    // MFMA C/D
typedef __attribute__((ext_vector_type(4))) unsigned short u16x4;

constexpr int B  = 4;
constexpr int S  = 2048;
constexpr int H  = 16;
constexpr int DM = 1024;
constexpr int M  = B * S;  // 8192

__device__ __forceinline__ unsigned short f2bf(float f) {
    union { float f; unsigned u; } v; v.f = f;
    unsigned r = v.u + 0x7FFFu + ((v.u >> 16) & 1u);  // RNE, finite inputs
    return (unsigned short)(r >> 16);
}

__device__ __forceinline__ void gload16(const void* g, void* l) {
    __builtin_amdgcn_global_load_lds(
        (const __attribute__((address_space(1))) void*)g,
        (__attribute__((address_space(3))) void*)l, 16, 0, 0);
}

// ---------------------------------------------------------------------------
// x fp32 -> bf16, 8 elems/thread
__global__ __launch_bounds__(256) void cast_x_kernel(
    const float* __restrict__ in, unsigned short* __restrict__ out)
{
    const size_t i = (size_t)blockIdx.x * 256 + threadIdx.x;
    const float4* p = (const float4*)in;
    float4 a = p[2 * i], b = p[2 * i + 1];
    short8 o;
    o[0] = (short)f2bf(a.x); o[1] = (short)f2bf(a.y);
    o[2] = (short)f2bf(a.z); o[3] = (short)f2bf(a.w);
    o[4] = (short)f2bf(b.x); o[5] = (short)f2bf(b.y);
    o[6] = (short)f2bf(b.z); o[7] = (short)f2bf(b.w);
    *(short8*)(out + 8 * i) = o;
}

// W[k][n] fp32 -> Wt[n][k] bf16 (32x32 tiles)
__global__ __launch_bounds__(256) void transpose_cast_w(
    const float* __restrict__ W, unsigned short* __restrict__ Wt)
{
    __shared__ float tile[32][33];
    const int t = threadIdx.x;
    const int r0 = blockIdx.y * 32, c0 = blockIdx.x * 32;
    {
        const int r = t >> 3, c4 = (t & 7) * 4;
        float4 a = *(const float4*)&W[(size_t)(r0 + r) * 1024 + c0 + c4];
        tile[r][c4 + 0] = a.x; tile[r][c4 + 1] = a.y;
        tile[r][c4 + 2] = a.z; tile[r][c4 + 3] = a.w;
    }
    __syncthreads();
    {
        const int n = t >> 3, k4 = (t & 7) * 4;
        u16x4 o;
        o[0] = f2bf(tile[k4 + 0][n]); o[1] = f2bf(tile[k4 + 1][n]);
        o[2] = f2bf(tile[k4 + 2][n]); o[3] = f2bf(tile[k4 + 3][n]);
        *(u16x4*)&Wt[(size_t)(c0 + n) * 1024 + r0 + k4] = o;
    }
}

// V [b,h,s,64] bf16 -> Vt [b,h,64,s] bf16 (64x64 tiles)
__global__ __launch_bounds__(256) void transpose_v(
    const unsigned short* __restrict__ V, unsigned short* __restrict__ Vt)
{
    __shared__ unsigned short tile[64][68];
    const int t = threadIdx.x;
    const int s0 = blockIdx.x * 64;
    const int bh = blockIdx.y;
    const size_t ibase = (size_t)bh * S * 64;
    #pragma unroll
    for (int i = 0; i < 4; ++i) {
        int idx = t + i * 256;
        int row = idx >> 4, d4 = (idx & 15) * 4;
        u16x4 a = *(const u16x4*)&V[ibase + (size_t)(s0 + row) * 64 + d4];
        tile[row][d4 + 0] = a[0]; tile[row][d4 + 1] = a[1];
        tile[row][d4 + 2] = a[2]; tile[row][d4 + 3] = a[3];
    }
    __syncthreads();
    const size_t obase = (size_t)bh * 64 * S;
    #pragma unroll
    for (int i = 0; i < 4; ++i) {
        int idx = t + i * 256;
        int dr = idx >> 4, s4 = (idx & 15) * 4;
        u16x4 o;
        o[0] = tile[s4 + 0][dr]; o[1] = tile[s4 + 1][dr];
        o[2] = tile[s4 + 2][dr]; o[3] = tile[s4 + 3][dr];
        *(u16x4*)&Vt[obase + (size_t)dr * S + s0 + s4] = o;
    }
}

// ---------------------------------------------------------------------------
// GEMM: X[M,1024]bf16 @ Wt[n][k]bf16 + bias.
// MODE 0: dst bf16 [b,h,s,64], value=(acc+bias)*scale.   MODE 1: dst fp32 [M,1024].
// 128x128 tile, BK=32, 4 waves (2x2), global_load_lds w=16, XOR-swizzled LDS.
template <int MODE>
__global__ __launch_bounds__(256) void gemm_bf16(
    const unsigned short* __restrict__ X, const unsigned short* __restrict__ Wt,
    const float* __restrict__ bias, void* __restrict__ dst, float scale)
{
    __shared__ __align__(16) unsigned short As[128 * 32];  // [row][k] 64B rows
    __shared__ __align__(16) unsigned short Bs[128 * 32];  // [n][k]

    const int t = threadIdx.x;
    const int lane = t & 63, w = t >> 6;
    const int wr = w >> 1, wc = w & 1;
    const int l15 = lane & 15, lhi = lane >> 4;
    const int row0 = blockIdx.y * 128, col0 = blockIdx.x * 128;

    const f32x4 z = {0.f, 0.f, 0.f, 0.f};
    f32x4 acc[4][4];
    #pragma unroll
    for (int i = 0; i < 4; ++i)
        #pragma unroll
        for (int j = 0; j < 4; ++j) acc[i][j] = z;

    // fragment chunk (swizzled): chunk' = (k-chunk) ^ ((row>>1)&3); row low bits = l15
    const int fchunk = ((lhi ^ ((l15 >> 1) & 3)) << 4);  // byte offset in 64B row

    for (int k0 = 0; k0 < 1024; k0 += 32) {
        __syncthreads();  // LDS safe to overwrite
        #pragma unroll
        for (int i = 0; i < 2; ++i) {
            int seg = t + i * 256;
            int row = seg >> 2;
            int ch  = (seg & 3) ^ ((row >> 1) & 3);  // pre-swizzled global source
            gload16(X  + (size_t)(row0 + row) * 1024 + k0 + ch * 8, (char*)As + seg * 16);
            gload16(Wt + (size_t)(col0 + row) * 1024 + k0 + ch * 8, (char*)Bs + seg * 16);
        }
        __syncthreads();  // staged (compiler drains vmcnt before barrier)

        short8 a[4], b[4];
        #pragma unroll
        for (int mi = 0; mi < 4; ++mi)
            a[mi] = *(const short8*)((const char*)As + (wr * 64 + mi * 16 + l15) * 64 + fchunk);
        #pragma unroll
        for (int ni = 0; ni < 4; ++ni)
            b[ni] = *(const short8*)((const char*)Bs + (wc * 64 + ni * 16 + l15) * 64 + fchunk);
        #pragma unroll
        for (int mi = 0; mi < 4; ++mi)
            #pragma unroll
            for (int ni = 0; ni < 4; ++ni)
                acc[mi][ni] = __builtin_amdgcn_mfma_f32_16x16x32_bf16(
                    a[mi], b[ni], acc[mi][ni], 0, 0, 0);
    }

    #pragma unroll
    for (int mi = 0; mi < 4; ++mi)
        #pragma unroll
        for (int ni = 0; ni < 4; ++ni) {
            const int cc = col0 + wc * 64 + ni * 16 + l15;
            const float bv = bias[cc];
            #pragma unroll
            for (int r = 0; r < 4; ++r) {
                const int rr = row0 + wr * 64 + mi * 16 + lhi * 4 + r;
                const float val = acc[mi][ni][r] + bv;
                if (MODE == 0) {
                    // [b,h,s,d]
                    ((unsigned short*)dst)[((((size_t)(rr >> 11) * 16 + (cc >> 6)) * 2048
                                            + (rr & 2047)) << 6) + (cc & 63)]
                        = f2bf(val * scale);
                } else {
                    ((float*)dst)[(size_t)rr * 1024 + cc] = val;
                }
            }
        }
}

// ---------------------------------------------------------------------------
// Flash causal attention, bf16 MFMA. Q,K [b,h,s,64] (Q pre-scaled by
// 0.125*log2e), Vt [b,h,64,s]. Out bf16 [b,s,h*64+d] == [M,1024].
// 256 thr = 4 waves; q-tile 128 (32 rows/wave), kv-tile 64.
__global__ __launch_bounds__(256) void attn_mfma(
    const unsigned short* __restrict__ Q, const unsigned short* __restrict__ K,
    const unsigned short* __restrict__ Vt, unsigned short* __restrict__ Out)
{
    __shared__ __align__(16) unsigned short Ks[64 * 64];   // [kv][d], 128B rows, swz
    __shared__ __align__(16) unsigned short Vs[64 * 64];   // [d][kv], 128B rows, swz
    __shared__ __align__(16) unsigned short Ps[128 * 64];  // [q][kv] bf16, swz

    const int t = threadIdx.x, lane = t & 63, w = t >> 6;
    const int l15 = lane & 15, lhi = lane >> 4, l7 = lane & 7;
    const int bx = blockIdx.x, bh = blockIdx.y;
    const int q0 = bx * 128;
    const size_t base = (size_t)bh * S * 64;

    // Q fragments in registers (A-operand): rows w*32+mi*16+l15, k=d
    short8 aq[2][2];
    #pragma unroll
    for (int mi = 0; mi < 2; ++mi)
        #pragma unroll
        for (int ks = 0; ks < 2; ++ks)
            aq[mi][ks] = *(const short8*)(Q + base
                + (size_t)(q0 + w * 32 + mi * 16 + l15) * 64 + ks * 32 + lhi * 8);

    const f32x4 z = {0.f, 0.f, 0.f, 0.f};
    f32x4 o4[2][4];
    float mrow[2][4], lrow[2][4];
    #pragma unroll
    for (int mi = 0; mi < 2; ++mi) {
        #pragma unroll
        for (int nd = 0; nd < 4; ++nd) o4[mi][nd] = z;
        #pragma unroll
        for (int r = 0; r < 4; ++r) { mrow[mi][r] = -INFINITY; lrow[mi][r] = 0.f; }
    }

    const int ntiles = 2 * bx + 2;  // causal
    for (int kt = 0; kt < ntiles; ++kt) {
        const int k0 = kt * 64;
        __syncthreads();  // Ks/Vs/Ps safe to overwrite
        #pragma unroll
        for (int i = 0; i < 2; ++i) {
            int seg = t + i * 256;
            int row = seg >> 3;
            int ch  = (seg & 7) ^ (row & 7);  // pre-swizzled source
            gload16(K + base + (size_t)(k0 + row) * 64 + ch * 8, (char*)Ks + seg * 16);
            gload16(Vt + ((size_t)bh * 64 + row) * S + k0 + ch * 8, (char*)Vs + seg * 16);
        }
        __syncthreads();

        // QK^T: sc[mi][ni] over kv cols ni*16+l15, rows lhi*4+r
        f32x4 sc[2][4];
        #pragma unroll
        for (int mi = 0; mi < 2; ++mi)
            #pragma unroll
            for (int ni = 0; ni < 4; ++ni) sc[mi][ni] = z;
        #pragma unroll
        for (int ks = 0; ks < 2; ++ks)
            #pragma unroll
            for (int ni = 0; ni < 4; ++ni) {
                short8 bk = *(const short8*)((const char*)Ks
                    + (ni * 16 + l15) * 128 + (((ks * 4 + lhi) ^ l7) << 4));
                #pragma unroll
                for (int mi = 0; mi < 2; ++mi)
                    sc[mi][ni] = __builtin_amdgcn_mfma_f32_16x16x32_bf16(
                        aq[mi][ks], bk, sc[mi][ni], 0, 0, 0);
            }

        if (kt >= ntiles - 2) {  // diagonal-overlap tiles only
            #pragma unroll
            for (int mi = 0; mi < 2; ++mi)
                #pragma unroll
                for (int ni = 0; ni < 4; ++ni)
                    #pragma unroll
                    for (int r = 0; r < 4; ++r) {
                        int qg = q0 + w * 32 + mi * 16 + lhi * 4 + r;
                        int kv = k0 + ni * 16 + l15;
                        if (kv > qg) sc[mi][ni][r] = -INFINITY;
                    }
        }

        // online softmax (log2 domain; scores already *log2e), write P bf16
        float al[2][4];
        #pragma unroll
        for (int mi = 0; mi < 2; ++mi) {
            const int prow_base = w * 32 + mi * 16 + lhi * 4;
            #pragma unroll
            for (int r = 0; r < 4; ++r) {
                float mx = fmaxf(fmaxf(sc[mi][0][r], sc[mi][1][r]),
                                 fmaxf(sc[mi][2][r], sc[mi][3][r]));
                #pragma unroll
                for (int off = 1; off < 16; off <<= 1)
                    mx = fmaxf(mx, __shfl_xor(mx, off));
                const float mnew = fmaxf(mrow[mi][r], mx);
                const float a = exp2f(mrow[mi][r] - mnew);
                const int prow = prow_base + r;
                const int swz = prow & 7;
                float ps = 0.f;
                #pragma unroll
                for (int ni = 0; ni < 4; ++ni) {
                    float pp = exp2f(sc[mi][ni][r] - mnew);
                    ps += pp;
                    *(unsigned short*)((char*)Ps + prow * 128
                        + (((ni * 2 + (l15 >> 3)) ^ swz) << 4) + l7 * 2) = f2bf(pp);
                }
                #pragma unroll
                for (int off = 1; off < 16; off <<= 1)
                    ps += __shfl_xor(ps, off);
                lrow[mi][r] = lrow[mi][r] * a + ps;
                mrow[mi][r] = mnew;
                al[mi][r] = a;
            }
        }
        #pragma unroll
        for (int mi = 0; mi < 2; ++mi)
            #pragma unroll
            for (int nd = 0; nd < 4; ++nd)
                #pragma unroll
                for (int r = 0; r < 4; ++r) o4[mi][nd][r] *= al[mi][r];

        __syncthreads();  // Ps visible

        // PV: O += P @ V  (A from Ps, B rows of Vs [d][kv])
        #pragma unroll
        for (int ks = 0; ks < 2; ++ks) {
            short8 pa[2];
            #pragma unroll
            for (int mi = 0; mi < 2; ++mi)
                pa[mi] = *(const short8*)((const char*)Ps
                    + (w * 32 + mi * 16 + l15) * 128 + (((ks * 4 + lhi) ^ l7) << 4));
            #pragma unroll
            for (int nd = 0; nd < 4; ++nd) {
                short8 bv = *(const short8*)((const char*)Vs
                    + (nd * 16 + l15) * 128 + (((ks * 4 + lhi) ^ l7) << 4));
                #pragma unroll
                for (int mi = 0; mi < 2; ++mi)
                    o4[mi][nd] = __builtin_amdgcn_mfma_f32_16x16x32_bf16(
                        pa[mi], bv, o4[mi][nd], 0, 0, 0);
            }
        }
    }

    // normalize + store bf16 to [b, s, h*64+d]
    const int b_ = bh >> 4, h_ = bh & 15;
    #pragma unroll
    for (int mi = 0; mi < 2; ++mi)
        #pragma unroll
        for (int r = 0; r < 4; ++r) {
            const float inv = 1.0f / lrow[mi][r];
            const int s_ = q0 + w * 32 + mi * 16 + lhi * 4 + r;
            #pragma unroll
            for (int nd = 0; nd < 4; ++nd)
                Out[(size_t)(b_ * S + s_) * 1024 + h_ * 64 + nd * 16 + l15]
                    = f2bf(o4[mi][nd][r] * inv);
        }
}

// ---------------------------------------------------------------------------
extern "C" void kernel_launch(void* const* d_in, const int* in_sizes, int n_in,
                              void* d_out, int out_size, void* d_ws, size_t ws_size,
                              hipStream_t stream)
{
    const float* x  = (const float*)d_in[0];
    // d_in[1] = attn_mask — causal, handled analytically
    const float* Wq = (const float*)d_in[2];
    const float* bq = (const float*)d_in[3];
    const float* Wk = (const float*)d_in[4];
    const float* bk = (const float*)d_in[5];
    const float* Wv = (const float*)d_in[6];
    const float* bv = (const float*)d_in[7];
    const float* Wo = (const float*)d_in[8];
    const float* bo = (const float*)d_in[9];
    float* out = (float*)d_out;

    unsigned short* p = (unsigned short*)d_ws;
    unsigned short* xb  = p; p += (size_t)M * DM;
    unsigned short* wqt = p; p += (size_t)DM * DM;
    unsigned short* wkt = p; p += (size_t)DM * DM;
    unsigned short* wvt = p; p += (size_t)DM * DM;
    unsigned short* wot = p; p += (size_t)DM * DM;
    unsigned short* qb  = p; p += (size_t)M * DM;
    unsigned short* kb  = p; p += (size_t)M * DM;
    unsigned short* vb  = p; p += (size_t)M * DM;
    unsigned short* vtb = p; p += (size_t)M * DM;
    unsigned short* attnb = p;

    cast_x_kernel<<<M * DM / 8 / 256, 256, 0, stream>>>(x, xb);
    transpose_cast_w<<<dim3(32, 32), 256, 0, stream>>>(Wq, wqt);
    transpose_cast_w<<<dim3(32, 32), 256, 0, stream>>>(Wk, wkt);
    transpose_cast_w<<<dim3(32, 32), 256, 0, stream>>>(Wv, wvt);
    transpose_cast_w<<<dim3(32, 32), 256, 0, stream>>>(Wo, wot);

    // fold 1/sqrt(dk) * log2(e) into Q so softmax runs in exp2 domain
    const float qscale = 0.125f * 1.44269504088896340736f;
    gemm_bf16<0><<<dim3(8, 64), 256, 0, stream>>>(xb, wqt, bq, qb, qscale);
    gemm_bf16<0><<<dim3(8, 64), 256, 0, stream>>>(xb, wkt, bk, kb, 1.0f);
    gemm_bf16<0><<<dim3(8, 64), 256, 0, stream>>>(xb, wvt, bv, vb, 1.0f);

    transpose_v<<<dim3(S / 64, B * H), 256, 0, stream>>>(vb, vtb);
    attn_mfma<<<dim3(S / 128, B * H), 256, 0, stream>>>(qb, kb, vtb, attnb);

    gemm_bf16<1><<<dim3(8, 64), 256, 0, stream>>>(attnb, wot, bo, out, 1.0f);
}

// Round 4
// 350.970 us; speedup vs baseline: 7.0600x; 1.3694x over previous
//
#include <hip/hip_runtime.h>
#include <math.h>

// MultiHeadAttn bf16-MFMA pipeline for MI355X (gfx950), round 4.
// attn rewritten: swapped-QKT in-register softmax, P-in-registers PV via
// 16x16x16 MFMA, double-buffered staging, balanced 1D grid.

typedef __attribute__((ext_vector_type(8))) short short8;   // 8 bf16 = 4 VGPR
typedef __attribute__((ext_vector_type(4))) short s16x4;    // 4 bf16 = 2 VGPR
typedef __attribute__((ext_vector_type(4))) float f32x4;    // MFMA C/D
typedef __attribute__((ext_vector_type(4))) unsigned short u16x4;

constexpr int B  = 4;
constexpr int S  = 2048;
constexpr int H  = 16;
constexpr int DM = 1024;
constexpr int M  = B * S;  // 8192

__device__ __forceinline__ unsigned short f2bf(float f) {
    union { float f; unsigned u; } v; v.f = f;
    unsigned r = v.u + 0x7FFFu + ((v.u >> 16) & 1u);  // RNE, finite inputs
    return (unsigned short)(r >> 16);
}

__device__ __forceinline__ void gload16(const void* g, void* l) {
    __builtin_amdgcn_global_load_lds(
        (const __attribute__((address_space(1))) void*)g,
        (__attribute__((address_space(3))) void*)l, 16, 0, 0);
}

__device__ __forceinline__ f32x4 mfma_16x16x16(s16x4 a, s16x4 b, f32x4 c) {
#if __has_builtin(__builtin_amdgcn_mfma_f32_16x16x16bf16_1k)
    return __builtin_amdgcn_mfma_f32_16x16x16bf16_1k(a, b, c, 0, 0, 0);
#else
    asm("v_mfma_f32_16x16x16_bf16 %0, %1, %2, %0" : "+v"(c) : "v"(a), "v"(b));
    return c;
#endif
}

// ---------------------------------------------------------------------------
// x fp32 -> bf16, 8 elems/thread
__global__ __launch_bounds__(256) void cast_x_kernel(
    const float* __restrict__ in, unsigned short* __restrict__ out)
{
    const size_t i = (size_t)blockIdx.x * 256 + threadIdx.x;
    const float4* p = (const float4*)in;
    float4 a = p[2 * i], b = p[2 * i + 1];
    short8 o;
    o[0] = (short)f2bf(a.x); o[1] = (short)f2bf(a.y);
    o[2] = (short)f2bf(a.z); o[3] = (short)f2bf(a.w);
    o[4] = (short)f2bf(b.x); o[5] = (short)f2bf(b.y);
    o[6] = (short)f2bf(b.z); o[7] = (short)f2bf(b.w);
    *(short8*)(out + 8 * i) = o;
}

// W[k][n] fp32 -> Wt[n][k] bf16 (32x32 tiles)
__global__ __launch_bounds__(256) void transpose_cast_w(
    const float* __restrict__ W, unsigned short* __restrict__ Wt)
{
    __shared__ float tile[32][33];
    const int t = threadIdx.x;
    const int r0 = blockIdx.y * 32, c0 = blockIdx.x * 32;
    {
        const int r = t >> 3, c4 = (t & 7) * 4;
        float4 a = *(const float4*)&W[(size_t)(r0 + r) * 1024 + c0 + c4];
        tile[r][c4 + 0] = a.x; tile[r][c4 + 1] = a.y;
        tile[r][c4 + 2] = a.z; tile[r][c4 + 3] = a.w;
    }
    __syncthreads();
    {
        const int n = t >> 3, k4 = (t & 7) * 4;
        u16x4 o;
        o[0] = f2bf(tile[k4 + 0][n]); o[1] = f2bf(tile[k4 + 1][n]);
        o[2] = f2bf(tile[k4 + 2][n]); o[3] = f2bf(tile[k4 + 3][n]);
        *(u16x4*)&Wt[(size_t)(c0 + n) * 1024 + r0 + k4] = o;
    }
}

// ---------------------------------------------------------------------------
// GEMM: X[M,1024]bf16 @ Wt[n][k]bf16 + bias.
// MODE 0: dst bf16 [b,h,s,64], value=(acc+bias)*scale.
// MODE 1: dst fp32 [M,1024].
// MODE 2: dst bf16 [b,h,d,s]  (V transposed at source; packed 4-s stores).
// 128x128 tile, BK=32, 4 waves (2x2), global_load_lds w=16, XOR-swizzled LDS.
template <int MODE>
__global__ __launch_bounds__(256) void gemm_bf16(
    const unsigned short* __restrict__ X, const unsigned short* __restrict__ Wt,
    const float* __restrict__ bias, void* __restrict__ dst, float scale)
{
    __shared__ __align__(16) unsigned short As[128 * 32];  // [row][k] 64B rows
    __shared__ __align__(16) unsigned short Bs[128 * 32];  // [n][k]

    const int t = threadIdx.x;
    const int lane = t & 63, w = t >> 6;
    const int wr = w >> 1, wc = w & 1;
    const int l15 = lane & 15, lhi = lane >> 4;
    const int row0 = blockIdx.y * 128, col0 = blockIdx.x * 128;

    const f32x4 z = {0.f, 0.f, 0.f, 0.f};
    f32x4 acc[4][4];
    #pragma unroll
    for (int i = 0; i < 4; ++i)
        #pragma unroll
        for (int j = 0; j < 4; ++j) acc[i][j] = z;

    const int fchunk = ((lhi ^ ((l15 >> 1) & 3)) << 4);  // byte offset in 64B row

    for (int k0 = 0; k0 < 1024; k0 += 32) {
        __syncthreads();
        #pragma unroll
        for (int i = 0; i < 2; ++i) {
            int seg = t + i * 256;
            int row = seg >> 2;
            int ch  = (seg & 3) ^ ((row >> 1) & 3);  // pre-swizzled global source
            gload16(X  + (size_t)(row0 + row) * 1024 + k0 + ch * 8, (char*)As + seg * 16);
            gload16(Wt + (size_t)(col0 + row) * 1024 + k0 + ch * 8, (char*)Bs + seg * 16);
        }
        __syncthreads();

        short8 a[4], b[4];
        #pragma unroll
        for (int mi = 0; mi < 4; ++mi)
            a[mi] = *(const short8*)((const char*)As + (wr * 64 + mi * 16 + l15) * 64 + fchunk);
        #pragma unroll
        for (int ni = 0; ni < 4; ++ni)
            b[ni] = *(const short8*)((const char*)Bs + (wc * 64 + ni * 16 + l15) * 64 + fchunk);
        #pragma unroll
        for (int mi = 0; mi < 4; ++mi)
            #pragma unroll
            for (int ni = 0; ni < 4; ++ni)
                acc[mi][ni] = __builtin_amdgcn_mfma_f32_16x16x32_bf16(
                    a[mi], b[ni], acc[mi][ni], 0, 0, 0);
    }

    #pragma unroll
    for (int mi = 0; mi < 4; ++mi)
        #pragma unroll
        for (int ni = 0; ni < 4; ++ni) {
            const int cc = col0 + wc * 64 + ni * 16 + l15;
            const float bv = bias[cc];
            if constexpr (MODE == 2) {
                // 4 consecutive s at fixed (b,h,d): one 8B store
                const int rr0 = row0 + wr * 64 + mi * 16 + lhi * 4;
                const int b0 = rr0 >> 11, s0_ = rr0 & 2047;
                u16x4 pv;
                pv[0] = f2bf(acc[mi][ni][0] + bv);
                pv[1] = f2bf(acc[mi][ni][1] + bv);
                pv[2] = f2bf(acc[mi][ni][2] + bv);
                pv[3] = f2bf(acc[mi][ni][3] + bv);
                *(u16x4*)&((unsigned short*)dst)[
                    (((size_t)(b0 * 16 + (cc >> 6)) * 64 + (cc & 63)) << 11) + s0_] = pv;
            } else {
                #pragma unroll
                for (int r = 0; r < 4; ++r) {
                    const int rr = row0 + wr * 64 + mi * 16 + lhi * 4 + r;
                    const float val = acc[mi][ni][r] + bv;
                    if constexpr (MODE == 0) {
                        ((unsigned short*)dst)[((((size_t)(rr >> 11) * 16 + (cc >> 6)) * 2048
                                                + (rr & 2047)) << 6) + (cc & 63)]
                            = f2bf(val * scale);
                    } else {
                        ((float*)dst)[(size_t)rr * 1024 + cc] = val;
                    }
                }
            }
        }
}

// ---------------------------------------------------------------------------
// Flash causal attention v2. Q,K [b,h,s,64] (Q pre-scaled by 0.125*log2e),
// Vt [b,h,64,s]. Out bf16 [b,s,h*64+d] == [M,1024].
// 256 thr = 4 waves, q-tile 128 (32 q/wave as 2x16), kv-tile 64.
// Swapped QK^T: sc[kv-row][q-col] -> lane (q=l15) owns its softmax row in reg.
// PV swapped: O^T[d][q] via 16x16x16 MFMA; P packed in-lane, never in LDS.
// Grid: 1D 1024, id -> (bx=id>>6, bh=id&63) for CU load balance + L2 share.
__global__ __launch_bounds__(256) void attn_mfma(
    const unsigned short* __restrict__ Q, const unsigned short* __restrict__ K,
    const unsigned short* __restrict__ Vt, unsigned short* __restrict__ Out)
{
    __shared__ __align__(16) unsigned short Ks[2][64 * 64];  // [buf][kv][d] swz
    __shared__ __align__(16) unsigned short Vs[2][64 * 64];  // [buf][d][kv] swz

    const int t = threadIdx.x, lane = t & 63, w = t >> 6;
    const int l15 = lane & 15, lhi = lane >> 4;
    const int id = blockIdx.x;
    const int bx = id >> 6, bh = id & 63;
    const int q0 = bx * 128;
    const size_t base = (size_t)bh * S * 64;

    // Q as B-operand fragments: col=q=l15, k=d=lhi*8.. (identical bytes to A-use)
    short8 bq[2][2];
    #pragma unroll
    for (int mi = 0; mi < 2; ++mi)
        #pragma unroll
        for (int ks = 0; ks < 2; ++ks)
            bq[mi][ks] = *(const short8*)(Q + base
                + (size_t)(q0 + w * 32 + mi * 16 + l15) * 64 + ks * 32 + lhi * 8);

    const f32x4 z = {0.f, 0.f, 0.f, 0.f};
    f32x4 o[2][4];  // [mi][dblk]; rows d=dblk*16+lhi*4+r, col q=l15
    float mrow[2] = {-INFINITY, -INFINITY}, lrow[2] = {0.f, 0.f};
    #pragma unroll
    for (int mi = 0; mi < 2; ++mi)
        #pragma unroll
        for (int d = 0; d < 4; ++d) o[mi][d] = z;

    auto STAGE = [&](int buf, int kt) {
        const int k0 = kt * 64;
        #pragma unroll
        for (int i = 0; i < 2; ++i) {
            int seg = t + i * 256;
            int row = seg >> 3;
            int ch  = (seg & 7) ^ (row & 7);  // pre-swizzled source
            gload16(K + base + (size_t)(k0 + row) * 64 + ch * 8,
                    (char*)Ks[buf] + seg * 16);
            gload16(Vt + ((size_t)bh * 64 + row) * S + k0 + ch * 8,
                    (char*)Vs[buf] + seg * 16);
        }
    };

    const int ntiles = 2 * bx + 2;  // causal
    STAGE(0, 0);
    __syncthreads();

    for (int kt = 0; kt < ntiles; ++kt) {
        const int cur = kt & 1;
        const int k0 = kt * 64;
        if (kt + 1 < ntiles) STAGE(cur ^ 1, kt + 1);

        // QK^T swapped: sc[mi][ni] = K-tile(ni) x Q(mi); rows kv, col q
        f32x4 sc[2][4];
        #pragma unroll
        for (int mi = 0; mi < 2; ++mi)
            #pragma unroll
            for (int ni = 0; ni < 4; ++ni) sc[mi][ni] = z;
        #pragma unroll
        for (int ks = 0; ks < 2; ++ks)
            #pragma unroll
            for (int ni = 0; ni < 4; ++ni) {
                short8 ak = *(const short8*)((const char*)Ks[cur]
                    + (ni * 16 + l15) * 128 + (((ks * 4 + lhi) ^ (l15 & 7)) << 4));
                #pragma unroll
                for (int mi = 0; mi < 2; ++mi)
                    sc[mi][ni] = __builtin_amdgcn_mfma_f32_16x16x32_bf16(
                        ak, bq[mi][ks], sc[mi][ni], 0, 0, 0);
            }

        if (k0 >= q0) {  // diagonal-overlap tiles
            #pragma unroll
            for (int mi = 0; mi < 2; ++mi) {
                const int qg = q0 + w * 32 + mi * 16 + l15;
                #pragma unroll
                for (int ni = 0; ni < 4; ++ni)
                    #pragma unroll
                    for (int r = 0; r < 4; ++r)
                        if (k0 + ni * 16 + lhi * 4 + r > qg)
                            sc[mi][ni][r] = -INFINITY;
            }
        }

        // in-register online softmax (exp2 domain) + pack P to bf16
        s16x4 pf[2][4];
        #pragma unroll
        for (int mi = 0; mi < 2; ++mi) {
            float tm = -INFINITY;
            #pragma unroll
            for (int ni = 0; ni < 4; ++ni) {
                float a0 = fmaxf(sc[mi][ni][0], sc[mi][ni][1]);
                float a1 = fmaxf(sc[mi][ni][2], sc[mi][ni][3]);
                tm = fmaxf(tm, fmaxf(a0, a1));
            }
            tm = fmaxf(tm, __shfl_xor(tm, 16));
            tm = fmaxf(tm, __shfl_xor(tm, 32));
            const float mnew = fmaxf(mrow[mi], tm);
            const float alpha = exp2f(mrow[mi] - mnew);
            mrow[mi] = mnew;
            float ps = 0.f;
            #pragma unroll
            for (int ni = 0; ni < 4; ++ni) {
                #pragma unroll
                for (int r = 0; r < 4; ++r) {
                    float pp = exp2f(sc[mi][ni][r] - mnew);
                    sc[mi][ni][r] = pp;
                    ps += pp;
                }
                s16x4 pk;
                pk[0] = (short)f2bf(sc[mi][ni][0]);
                pk[1] = (short)f2bf(sc[mi][ni][1]);
                pk[2] = (short)f2bf(sc[mi][ni][2]);
                pk[3] = (short)f2bf(sc[mi][ni][3]);
                pf[mi][ni] = pk;
            }
            ps += __shfl_xor(ps, 16);
            ps += __shfl_xor(ps, 32);
            lrow[mi] = lrow[mi] * alpha + ps;
            #pragma unroll
            for (int d = 0; d < 4; ++d) {
                o[mi][d][0] *= alpha; o[mi][d][1] *= alpha;
                o[mi][d][2] *= alpha; o[mi][d][3] *= alpha;
            }
        }

        // PV swapped: O^T[d][q] += V^T[d][kv] @ P^T[kv][q], K=16 chunks (ni)
        #pragma unroll
        for (int ni = 0; ni < 4; ++ni) {
            #pragma unroll
            for (int db = 0; db < 4; ++db) {
                const int row = db * 16 + l15;
                const int slot = ((ni * 2 + (lhi >> 1)) ^ (l15 & 7));
                s16x4 av = *(const s16x4*)((const char*)Vs[cur]
                    + row * 128 + slot * 16 + (lhi & 1) * 8);
                #pragma unroll
                for (int mi = 0; mi < 2; ++mi)
                    o[mi][db] = mfma_16x16x16(av, pf[mi][ni], o[mi][db]);
            }
        }

        __syncthreads();  // next tile staged; buffers safe to swap
    }

    // normalize + store bf16 to [b, s, h*64+d]; lane q=l15, d runs per (db,r)
    const int b_ = bh >> 4, h_ = bh & 15;
    #pragma unroll
    for (int mi = 0; mi < 2; ++mi) {
        const float inv = 1.0f / lrow[mi];
        const int s_ = q0 + w * 32 + mi * 16 + l15;
        #pragma unroll
        for (int db = 0; db < 4; ++db) {
            u16x4 ov;
            ov[0] = f2bf(o[mi][db][0] * inv);
            ov[1] = f2bf(o[mi][db][1] * inv);
            ov[2] = f2bf(o[mi][db][2] * inv);
            ov[3] = f2bf(o[mi][db][3] * inv);
            *(u16x4*)&Out[(size_t)(b_ * S + s_) * 1024 + h_ * 64 + db * 16 + lhi * 4] = ov;
        }
    }
}

// ---------------------------------------------------------------------------
extern "C" void kernel_launch(void* const* d_in, const int* in_sizes, int n_in,
                              void* d_out, int out_size, void* d_ws, size_t ws_size,
                              hipStream_t stream)
{
    const float* x  = (const float*)d_in[0];
    // d_in[1] = attn_mask — causal, handled analytically
    const float* Wq = (const float*)d_in[2];
    const float* bq = (const float*)d_in[3];
    const float* Wk = (const float*)d_in[4];
    const float* bk = (const float*)d_in[5];
    const float* Wv = (const float*)d_in[6];
    const float* bv = (const float*)d_in[7];
    const float* Wo = (const float*)d_in[8];
    const float* bo = (const float*)d_in[9];
    float* out = (float*)d_out;

    unsigned short* p = (unsigned short*)d_ws;
    unsigned short* xb  = p; p += (size_t)M * DM;
    unsigned short* wqt = p; p += (size_t)DM * DM;
    unsigned short* wkt = p; p += (size_t)DM * DM;
    unsigned short* wvt = p; p += (size_t)DM * DM;
    unsigned short* wot = p; p += (size_t)DM * DM;
    unsigned short* qb  = p; p += (size_t)M * DM;
    unsigned short* kb  = p; p += (size_t)M * DM;
    unsigned short* vtb = p; p += (size_t)M * DM;
    unsigned short* attnb = p;

    cast_x_kernel<<<M * DM / 8 / 256, 256, 0, stream>>>(x, xb);
    transpose_cast_w<<<dim3(32, 32), 256, 0, stream>>>(Wq, wqt);
    transpose_cast_w<<<dim3(32, 32), 256, 0, stream>>>(Wk, wkt);
    transpose_cast_w<<<dim3(32, 32), 256, 0, stream>>>(Wv, wvt);
    transpose_cast_w<<<dim3(32, 32), 256, 0, stream>>>(Wo, wot);

    // fold 1/sqrt(dk) * log2(e) into Q so softmax runs in exp2 domain
    const float qscale = 0.125f * 1.44269504088896340736f;
    gemm_bf16<0><<<dim3(8, 64), 256, 0, stream>>>(xb, wqt, bq, qb, qscale);
    gemm_bf16<0><<<dim3(8, 64), 256, 0, stream>>>(xb, wkt, bk, kb, 1.0f);
    gemm_bf16<2><<<dim3(8, 64), 256, 0, stream>>>(xb, wvt, bv, vtb, 1.0f);

    attn_mfma<<<dim3(1024), 256, 0, stream>>>(qb, kb, vtb, attnb);

    gemm_bf16<1><<<dim3(8, 64), 256, 0, stream>>>(attnb, wot, bo, out, 1.0f);
}

// Round 5
// 314.457 us; speedup vs baseline: 7.8798x; 1.1161x over previous
//
#include <hip/hip_runtime.h>
#include <math.h>

// MultiHeadAttn bf16-MFMA pipeline for MI355X (gfx950), round 5.
// r5: GEMMs double-buffered (T3-minimum), QKV fused into one N=3072 GEMM,
// attn: cvt_pk P-packing (T12), defer-max (T13), PV bank-conflict fix
// (d-bit3 half-swap in Vt layout), fused weight transposes.

typedef __attribute__((ext_vector_type(8))) short short8;   // 8 bf16 = 4 VGPR
typedef __attribute__((ext_vector_type(4))) short s16x4;    // 4 bf16 = 2 VGPR
typedef __attribute__((ext_vector_type(4))) float f32x4;    // MFMA C/D
typedef __attribute__((ext_vector_type(4))) unsigned short u16x4;
typedef __attribute__((ext_vector_type(2))) unsigned int u32x2;

constexpr int B  = 4;
constexpr int S  = 2048;
constexpr int H  = 16;
constexpr int DM = 1024;
constexpr int M  = B * S;  // 8192

__device__ __forceinline__ unsigned short f2bf(float f) {
    union { float f; unsigned u; } v; v.f = f;
    unsigned r = v.u + 0x7FFFu + ((v.u >> 16) & 1u);  // RNE, finite inputs
    return (unsigned short)(r >> 16);
}

// 4x f32 -> 4x bf16 via v_cvt_pk_bf16_f32 (RNE), 2 instructions
__device__ __forceinline__ s16x4 pack_bf16x4(float a, float b, float c, float d) {
    unsigned r0, r1;
    asm("v_cvt_pk_bf16_f32 %0, %1, %2" : "=v"(r0) : "v"(a), "v"(b));
    asm("v_cvt_pk_bf16_f32 %0, %1, %2" : "=v"(r1) : "v"(c), "v"(d));
    u32x2 t; t[0] = r0; t[1] = r1;
    return __builtin_bit_cast(s16x4, t);
}

__device__ __forceinline__ void gload16(const void* g, void* l) {
    __builtin_amdgcn_global_load_lds(
        (const __attribute__((address_space(1))) void*)g,
        (__attribute__((address_space(3))) void*)l, 16, 0, 0);
}

__device__ __forceinline__ f32x4 mfma_16x16x16(s16x4 a, s16x4 b, f32x4 c) {
#if __has_builtin(__builtin_amdgcn_mfma_f32_16x16x16bf16_1k)
    return __builtin_amdgcn_mfma_f32_16x16x16bf16_1k(a, b, c, 0, 0, 0);
#else
    asm("v_mfma_f32_16x16x16_bf16 %0, %1, %2, %0" : "+v"(c) : "v"(a), "v"(b));
    return c;
#endif
}

// ---------------------------------------------------------------------------
// x fp32 -> bf16, 8 elems/thread
__global__ __launch_bounds__(256) void cast_x_kernel(
    const float* __restrict__ in, unsigned short* __restrict__ out)
{
    const size_t i = (size_t)blockIdx.x * 256 + threadIdx.x;
    const float4* p = (const float4*)in;
    float4 a = p[2 * i], b = p[2 * i + 1];
    short8 o;
    o[0] = (short)f2bf(a.x); o[1] = (short)f2bf(a.y);
    o[2] = (short)f2bf(a.z); o[3] = (short)f2bf(a.w);
    o[4] = (short)f2bf(b.x); o[5] = (short)f2bf(b.y);
    o[6] = (short)f2bf(b.z); o[7] = (short)f2bf(b.w);
    *(short8*)(out + 8 * i) = o;
}

// W[k][n] fp32 -> Wt[n][k] bf16 (32x32 tiles), 4 matrices via blockIdx.z
__global__ __launch_bounds__(256) void transpose_cast_w(
    const float* __restrict__ W0, const float* __restrict__ W1,
    const float* __restrict__ W2, const float* __restrict__ W3,
    unsigned short* __restrict__ T0, unsigned short* __restrict__ T1,
    unsigned short* __restrict__ T2, unsigned short* __restrict__ T3)
{
    const int z = blockIdx.z;
    const float* W = (z == 0) ? W0 : (z == 1) ? W1 : (z == 2) ? W2 : W3;
    unsigned short* Wt = (z == 0) ? T0 : (z == 1) ? T1 : (z == 2) ? T2 : T3;

    __shared__ float tile[32][33];
    const int t = threadIdx.x;
    const int r0 = blockIdx.y * 32, c0 = blockIdx.x * 32;
    {
        const int r = t >> 3, c4 = (t & 7) * 4;
        float4 a = *(const float4*)&W[(size_t)(r0 + r) * 1024 + c0 + c4];
        tile[r][c4 + 0] = a.x; tile[r][c4 + 1] = a.y;
        tile[r][c4 + 2] = a.z; tile[r][c4 + 3] = a.w;
    }
    __syncthreads();
    {
        const int n = t >> 3, k4 = (t & 7) * 4;
        u16x4 o;
        o[0] = f2bf(tile[k4 + 0][n]); o[1] = f2bf(tile[k4 + 1][n]);
        o[2] = f2bf(tile[k4 + 2][n]); o[3] = f2bf(tile[k4 + 3][n]);
        *(u16x4*)&Wt[(size_t)(c0 + n) * 1024 + r0 + k4] = o;
    }
}

// ---------------------------------------------------------------------------
// GEMM: X[M,1024]bf16 @ Wt[n][k]bf16 + bias. 128x128 tile, BK=32, 4 waves,
// double-buffered global_load_lds staging (prefetch ahead of compute).
// FUSED=1: N=3072 (wq|wk|wv rows contiguous). Columns 0-1023 -> Q bf16
//   [b,h,s,64] *qscale; 1024-2047 -> K bf16 [b,h,s,64]; 2048-3071 -> V bf16
//   [b,h,d,s] with d-bit3 half-granule swap (s ^= 4 when d&8) for attn PV.
// FUSED=0: dst fp32 [M,1024] (output projection).
template <int FUSED>
__global__ __launch_bounds__(256) void gemm_bf16(
    const unsigned short* __restrict__ X, const unsigned short* __restrict__ Wt,
    const float* __restrict__ bias_q, const float* __restrict__ bias_k,
    const float* __restrict__ bias_v,
    void* __restrict__ dq, void* __restrict__ dk, void* __restrict__ dv,
    float qscale)
{
    __shared__ __align__(16) unsigned short As[2][128 * 32];  // [buf][row][k]
    __shared__ __align__(16) unsigned short Bs[2][128 * 32];  // [buf][n][k]

    const int t = threadIdx.x;
    const int lane = t & 63, w = t >> 6;
    const int wr = w >> 1, wc = w & 1;
    const int l15 = lane & 15, lhi = lane >> 4;
    const int row0 = blockIdx.y * 128, col0 = blockIdx.x * 128;

    const f32x4 z = {0.f, 0.f, 0.f, 0.f};
    f32x4 acc[4][4];
    #pragma unroll
    for (int i = 0; i < 4; ++i)
        #pragma unroll
        for (int j = 0; j < 4; ++j) acc[i][j] = z;

    const int fchunk = ((lhi ^ ((l15 >> 1) & 3)) << 4);  // byte offset in 64B row

    auto STAGE = [&](int buf, int k0) {
        #pragma unroll
        for (int i = 0; i < 2; ++i) {
            int seg = t + i * 256;
            int row = seg >> 2;
            int ch  = (seg & 3) ^ ((row >> 1) & 3);  // pre-swizzled global source
            gload16(X  + (size_t)(row0 + row) * 1024 + k0 + ch * 8,
                    (char*)As[buf] + seg * 16);
            gload16(Wt + (size_t)(col0 + row) * 1024 + k0 + ch * 8,
                    (char*)Bs[buf] + seg * 16);
        }
    };

    STAGE(0, 0);
    for (int k0 = 0; k0 < 1024; k0 += 32) {
        const int cur = (k0 >> 5) & 1;
        __syncthreads();  // drains prefetch (vmcnt) + protects buf cur^1 reads
        if (k0 + 32 < 1024) STAGE(cur ^ 1, k0 + 32);

        short8 a[4], b[4];
        #pragma unroll
        for (int mi = 0; mi < 4; ++mi)
            a[mi] = *(const short8*)((const char*)As[cur]
                + (wr * 64 + mi * 16 + l15) * 64 + fchunk);
        #pragma unroll
        for (int ni = 0; ni < 4; ++ni)
            b[ni] = *(const short8*)((const char*)Bs[cur]
                + (wc * 64 + ni * 16 + l15) * 64 + fchunk);
        #pragma unroll
        for (int mi = 0; mi < 4; ++mi)
            #pragma unroll
            for (int ni = 0; ni < 4; ++ni)
                acc[mi][ni] = __builtin_amdgcn_mfma_f32_16x16x32_bf16(
                    a[mi], b[ni], acc[mi][ni], 0, 0, 0);
    }

    #pragma unroll
    for (int mi = 0; mi < 4; ++mi)
        #pragma unroll
        for (int ni = 0; ni < 4; ++ni) {
            const int cc = col0 + wc * 64 + ni * 16 + l15;
            if constexpr (FUSED == 1) {
                const int sel = cc >> 10;          // 0=Q 1=K 2=V, uniform/block
                const int hh = (cc >> 6) & 15, dd = cc & 63;
                const float bv = (sel == 0 ? bias_q : sel == 1 ? bias_k : bias_v)
                                 [cc & 1023];
                const int rr0 = row0 + wr * 64 + mi * 16 + lhi * 4;
                const int b0i = rr0 >> 11, s0_ = rr0 & 2047;
                if (sel == 2) {
                    // V^T [b,h,d,s] with half-granule swap: s ^= 4 when d&8
                    const int sstore = s0_ ^ (((cc >> 3) & 1) << 2);
                    s16x4 pv = pack_bf16x4(
                        acc[mi][ni][0] + bv, acc[mi][ni][1] + bv,
                        acc[mi][ni][2] + bv, acc[mi][ni][3] + bv);
                    *(s16x4*)&((unsigned short*)dv)[
                        (((size_t)(b0i * 16 + hh) * 64 + dd) << 11) + sstore] = pv;
                } else {
                    unsigned short* dst = (unsigned short*)(sel == 0 ? dq : dk);
                    const float sc_ = (sel == 0) ? qscale : 1.0f;
                    #pragma unroll
                    for (int r = 0; r < 4; ++r)
                        dst[(((size_t)(b0i * 16 + hh) * 2048 + s0_ + r) << 6) + dd]
                            = f2bf((acc[mi][ni][r] + bv) * sc_);
                }
            } else {
                const float bv = bias_q[cc];
                #pragma unroll
                for (int r = 0; r < 4; ++r) {
                    const int rr = row0 + wr * 64 + mi * 16 + lhi * 4 + r;
                    ((float*)dq)[(size_t)rr * 1024 + cc] = acc[mi][ni][r] + bv;
                }
            }
        }
}

// ---------------------------------------------------------------------------
// Flash causal attention v3. Q,K [b,h,s,64] (Q pre-scaled by 0.125*log2e),
// Vt [b,h,d,s] with d-bit3 half-swap. Out bf16 [b,s,h*64+d] == [M,1024].
// 256 thr = 4 waves, q-tile 128 (32 q/wave), kv-tile 64, dbuf staging.
// Swapped QK^T (lane q=l15 owns softmax row), in-reg softmax w/ defer-max,
// cvt_pk P-packing, PV via 16x16x16 MFMA (P never in LDS).
__global__ __launch_bounds__(256) void attn_mfma(
    const unsigned short* __restrict__ Q, const unsigned short* __restrict__ K,
    const unsigned short* __restrict__ Vt, unsigned short* __restrict__ Out)
{
    __shared__ __align__(16) unsigned short Ks[2][64 * 64];  // [buf][kv][d] swz
    __shared__ __align__(16) unsigned short Vs[2][64 * 64];  // [buf][d][kv] swz

    const int t = threadIdx.x, lane = t & 63, w = t >> 6;
    const int l15 = lane & 15, lhi = lane >> 4;
    const int id = blockIdx.x;
    const int bx = id >> 6, bh = id & 63;
    const int q0 = bx * 128;
    const size_t base = (size_t)bh * S * 64;

    // Q as B-operand fragments: col=q=l15, k=d
    short8 bq[2][2];
    #pragma unroll
    for (int mi = 0; mi < 2; ++mi)
        #pragma unroll
        for (int ks = 0; ks < 2; ++ks)
            bq[mi][ks] = *(const short8*)(Q + base
                + (size_t)(q0 + w * 32 + mi * 16 + l15) * 64 + ks * 32 + lhi * 8);

    const f32x4 z = {0.f, 0.f, 0.f, 0.f};
    f32x4 o[2][4];  // [mi][dblk]; rows d=dblk*16+lhi*4+r, col q=l15
    float mrow[2] = {-INFINITY, -INFINITY}, lrow[2] = {0.f, 0.f};
    #pragma unroll
    for (int mi = 0; mi < 2; ++mi)
        #pragma unroll
        for (int d = 0; d < 4; ++d) o[mi][d] = z;

    auto STAGE = [&](int buf, int kt) {
        const int k0 = kt * 64;
        #pragma unroll
        for (int i = 0; i < 2; ++i) {
            int seg = t + i * 256;
            int row = seg >> 3;
            int ch  = (seg & 7) ^ (row & 7);  // pre-swizzled source
            gload16(K + base + (size_t)(k0 + row) * 64 + ch * 8,
                    (char*)Ks[buf] + seg * 16);
            gload16(Vt + ((size_t)bh * 64 + row) * S + k0 + ch * 8,
                    (char*)Vs[buf] + seg * 16);
        }
    };

    const int ntiles = 2 * bx + 2;  // causal
    STAGE(0, 0);
    __syncthreads();

    for (int kt = 0; kt < ntiles; ++kt) {
        const int cur = kt & 1;
        const int k0 = kt * 64;
        if (kt + 1 < ntiles) STAGE(cur ^ 1, kt + 1);

        // QK^T swapped: rows kv, col q
        f32x4 sc[2][4];
        #pragma unroll
        for (int mi = 0; mi < 2; ++mi)
            #pragma unroll
            for (int ni = 0; ni < 4; ++ni) sc[mi][ni] = z;
        #pragma unroll
        for (int ks = 0; ks < 2; ++ks)
            #pragma unroll
            for (int ni = 0; ni < 4; ++ni) {
                short8 ak = *(const short8*)((const char*)Ks[cur]
                    + (ni * 16 + l15) * 128 + (((ks * 4 + lhi) ^ (l15 & 7)) << 4));
                #pragma unroll
                for (int mi = 0; mi < 2; ++mi)
                    sc[mi][ni] = __builtin_amdgcn_mfma_f32_16x16x32_bf16(
                        ak, bq[mi][ks], sc[mi][ni], 0, 0, 0);
            }

        if (k0 >= q0) {  // diagonal-overlap tiles
            #pragma unroll
            for (int mi = 0; mi < 2; ++mi) {
                const int qg = q0 + w * 32 + mi * 16 + l15;
                #pragma unroll
                for (int ni = 0; ni < 4; ++ni)
                    #pragma unroll
                    for (int r = 0; r < 4; ++r)
                        if (k0 + ni * 16 + lhi * 4 + r > qg)
                            sc[mi][ni][r] = -INFINITY;
            }
        }

        // in-register online softmax (exp2 domain) + defer-max + cvt_pk pack
        s16x4 pf[2][4];
        #pragma unroll
        for (int mi = 0; mi < 2; ++mi) {
            float tm = -INFINITY;
            #pragma unroll
            for (int ni = 0; ni < 4; ++ni) {
                float a0 = fmaxf(sc[mi][ni][0], sc[mi][ni][1]);
                float a1 = fmaxf(sc[mi][ni][2], sc[mi][ni][3]);
                tm = fmaxf(tm, fmaxf(a0, a1));
            }
            tm = fmaxf(tm, __shfl_xor(tm, 16));
            tm = fmaxf(tm, __shfl_xor(tm, 32));
            // defer-max (T13): rescale only if some lane grew by >8 (2^8 bound)
            if (!__all(tm <= mrow[mi] + 8.f)) {
                const float mnew = fmaxf(mrow[mi], tm);
                const float alpha = exp2f(mrow[mi] - mnew);
                mrow[mi] = mnew;
                lrow[mi] *= alpha;
                #pragma unroll
                for (int d = 0; d < 4; ++d) {
                    o[mi][d][0] *= alpha; o[mi][d][1] *= alpha;
                    o[mi][d][2] *= alpha; o[mi][d][3] *= alpha;
                }
            }
            float ps = 0.f;
            #pragma unroll
            for (int ni = 0; ni < 4; ++ni) {
                float p0 = exp2f(sc[mi][ni][0] - mrow[mi]);
                float p1 = exp2f(sc[mi][ni][1] - mrow[mi]);
                float p2 = exp2f(sc[mi][ni][2] - mrow[mi]);
                float p3 = exp2f(sc[mi][ni][3] - mrow[mi]);
                ps += (p0 + p1) + (p2 + p3);
                pf[mi][ni] = pack_bf16x4(p0, p1, p2, p3);
            }
            ps += __shfl_xor(ps, 16);
            ps += __shfl_xor(ps, 32);
            lrow[mi] += ps;
        }

        // PV swapped: O^T[d][q] += V^T[d][kv] @ P^T[kv][q]
        // half-swap read: half = (lhi&1) ^ (l15>>3) -> 32-bank coverage
        #pragma unroll
        for (int ni = 0; ni < 4; ++ni) {
            #pragma unroll
            for (int db = 0; db < 4; ++db) {
                const int row = db * 16 + l15;
                const int slot = ((ni * 2 + (lhi >> 1)) ^ (l15 & 7));
                const int half = (lhi & 1) ^ ((l15 >> 3) & 1);
                s16x4 av = *(const s16x4*)((const char*)Vs[cur]
                    + row * 128 + slot * 16 + half * 8);
                #pragma unroll
                for (int mi = 0; mi < 2; ++mi)
                    o[mi][db] = mfma_16x16x16(av, pf[mi][ni], o[mi][db]);
            }
        }

        __syncthreads();  // next tile staged; buffers safe to swap
    }

    // normalize + store bf16 to [b, s, h*64+d]; lane q=l15
    const int b_ = bh >> 4, h_ = bh & 15;
    #pragma unroll
    for (int mi = 0; mi < 2; ++mi) {
        const float inv = 1.0f / lrow[mi];
        const int s_ = q0 + w * 32 + mi * 16 + l15;
        #pragma unroll
        for (int db = 0; db < 4; ++db) {
            s16x4 ov = pack_bf16x4(o[mi][db][0] * inv, o[mi][db][1] * inv,
                                   o[mi][db][2] * inv, o[mi][db][3] * inv);
            *(s16x4*)&Out[(size_t)(b_ * S + s_) * 1024 + h_ * 64 + db * 16 + lhi * 4]
                = ov;
        }
    }
}

// ---------------------------------------------------------------------------
extern "C" void kernel_launch(void* const* d_in, const int* in_sizes, int n_in,
                              void* d_out, int out_size, void* d_ws, size_t ws_size,
                              hipStream_t stream)
{
    const float* x  = (const float*)d_in[0];
    // d_in[1] = attn_mask — causal, handled analytically
    const float* Wq = (const float*)d_in[2];
    const float* bq = (const float*)d_in[3];
    const float* Wk = (const float*)d_in[4];
    const float* bk = (const float*)d_in[5];
    const float* Wv = (const float*)d_in[6];
    const float* bv = (const float*)d_in[7];
    const float* Wo = (const float*)d_in[8];
    const float* bo = (const float*)d_in[9];
    float* out = (float*)d_out;

    unsigned short* p = (unsigned short*)d_ws;
    unsigned short* xb  = p; p += (size_t)M * DM;
    unsigned short* wqt = p; p += (size_t)DM * DM;   // wqt|wkt|wvt contiguous
    unsigned short* wkt = p; p += (size_t)DM * DM;
    unsigned short* wvt = p; p += (size_t)DM * DM;
    unsigned short* wot = p; p += (size_t)DM * DM;
    unsigned short* qb  = p; p += (size_t)M * DM;
    unsigned short* kb  = p; p += (size_t)M * DM;
    unsigned short* vtb = p; p += (size_t)M * DM;
    unsigned short* attnb = p;

    cast_x_kernel<<<M * DM / 8 / 256, 256, 0, stream>>>(x, xb);
    transpose_cast_w<<<dim3(32, 32, 4), 256, 0, stream>>>(
        Wq, Wk, Wv, Wo, wqt, wkt, wvt, wot);

    // fold 1/sqrt(dk) * log2(e) into Q so softmax runs in exp2 domain
    const float qscale = 0.125f * 1.44269504088896340736f;
    gemm_bf16<1><<<dim3(24, 64), 256, 0, stream>>>(
        xb, wqt, bq, bk, bv, qb, kb, vtb, qscale);

    attn_mfma<<<dim3(1024), 256, 0, stream>>>(qb, kb, vtb, attnb);

    gemm_bf16<0><<<dim3(8, 64), 256, 0, stream>>>(
        attnb, wot, bo, nullptr, nullptr, out, nullptr, nullptr, 1.0f);
}